// Round 4
// baseline (473.896 us; speedup 1.0000x reference)
//
#include <hip/hip_runtime.h>

// ---------------------------------------------------------------------------
// AttentionConvolution2D: B=2, DIN=128, H=W=256, BS=4 -> 64x64 tiles of 16
// tokens, NH=8, DH=32, DOUT=128.
//
//   prep_w   : w_in + w_out fp32 -> bf16 (ws)
//   qkv_proj : MFMA bf16 GEMM; x-fragments hoisted to registers (16 LDS reads
//              per thread total, not 192). q,k row-major per token; v written
//              transposed via swapped-operand MFMA (coalesced b64 stores).
//   attn_out : 512 threads, one head per wave; max-free softmax (scores are
//              bounded: |qk*scale| <~ 8, bias in [0,8] -> exp safe in fp32);
//              P stored UNNORMALIZED in LDS, normalization folded into the
//              PV epilogue via 4 shuffles. PV tail (keys 128..143) via a 5th
//              K=32 MFMA with the A-operand masked to zero on quads 2,3.
//              Fused MFMA out-projection. XCD-aware block swizzle.
// ---------------------------------------------------------------------------

typedef __bf16 bf16x8 __attribute__((ext_vector_type(8)));
typedef __bf16 bf16x2 __attribute__((ext_vector_type(2)));
typedef float f32x4 __attribute__((ext_vector_type(4)));

__device__ __forceinline__ unsigned pk2(float a, float b) {
  bf16x2 v;
  v[0] = (__bf16)a;
  v[1] = (__bf16)b;  // compiler emits v_cvt_pk_bf16_f32 (RNE) on gfx950
  return __builtin_bit_cast(unsigned, v);
}
__device__ __forceinline__ unsigned short bf1(float a) {
  __bf16 v = (__bf16)a;
  return __builtin_bit_cast(unsigned short, v);
}

// ---------------------------------------------------------------- prep -----
__global__ __launch_bounds__(256) void prep_w(const float* __restrict__ w_in,
                                              const float* __restrict__ w_out,
                                              unsigned short* __restrict__ wbf,
                                              unsigned short* __restrict__ wob) {
  int idx = (blockIdx.x * 256 + threadIdx.x) * 4;
  const float* src; unsigned short* dst; int off;
  if (idx < 98304) { src = w_in;  dst = wbf; off = idx; }
  else             { src = w_out; dst = wob; off = idx - 98304; }
  float4 v = *(const float4*)(src + off);
  uint2 o;
  o.x = pk2(v.x, v.y);
  o.y = pk2(v.z, v.w);
  *(uint2*)(dst + off) = o;
}

// ------------------------------------------------------------ qkv proj -----
// grid (16, 64, 2): blockIdx.x = 4-tile strip along w, y = vb, z = b.
#define XS_STRIDE 136  // 128 + 8 pad

__global__ __launch_bounds__(256, 4) void qkv_proj(const float* __restrict__ x,
                                                   const unsigned short* __restrict__ wbf,
                                                   const float* __restrict__ b_in,
                                                   unsigned short* __restrict__ qkv,
                                                   unsigned short* __restrict__ vT) {
  __shared__ __align__(16) unsigned short xs[64 * XS_STRIDE];
  const int tid = threadIdx.x;
  const int strip = blockIdx.x, vb = blockIdx.y, b = blockIdx.z;
  const int w0 = strip * 16;
  const size_t xbase = ((size_t)b * 128) * 65536 + (size_t)(vb * 4) * 256 + (size_t)w0;

  // Stage x tile: 128 c x (4 i1 x 16 w), token-major bf16 in LDS.
#pragma unroll
  for (int it = 0; it < 8; ++it) {
    int flat = (it * 256 + tid) * 4;   // [0, 8192)
    int c = flat >> 6;
    int rem = flat & 63;
    int i1 = rem >> 4;
    int lw0 = rem & 15;
    const float4 v = *(const float4*)(x + xbase + (size_t)c * 65536 + i1 * 256 + lw0);
    float vv[4] = {v.x, v.y, v.z, v.w};
#pragma unroll
    for (int e = 0; e < 4; ++e) {
      int lw = lw0 + e;
      int u = ((lw >> 2) << 4) + ((lw & 3) << 2) + i1;  // tile*16 + i0*4 + i1
      xs[u * XS_STRIDE + c] = bf1(vv[e]);
    }
  }
  __syncthreads();

  const int wv = tid >> 6, lane = tid & 63;
  const int l16 = lane & 15, q4 = lane >> 4;
  const size_t tile_base = ((size_t)(b * 64 + vb)) * 64 + strip * 4;

  // Hoist all 16 x-fragments (jt-invariant) into registers: 64 VGPRs.
  bf16x8 xf[4][4];
#pragma unroll
  for (int tt = 0; tt < 4; ++tt)
#pragma unroll
    for (int ks = 0; ks < 4; ++ks)
      xf[tt][ks] = *(const bf16x8*)(xs + (tt * 16 + l16) * XS_STRIDE + ks * 32 + q4 * 8);

#pragma unroll 1
  for (int jt = 0; jt < 12; ++jt) {
    const int j0 = wv * 192 + jt * 16;
    // w-row fragments: W[j0+l16][k=q4*8+e]
    bf16x8 wf[4];
    const unsigned short* wr = wbf + (size_t)(j0 + l16) * 128 + q4 * 8;
#pragma unroll
    for (int ks = 0; ks < 4; ++ks) wf[ks] = *(const bf16x8*)(wr + ks * 32);

    if (j0 < 512) {
      // ---- q,k: C[j][tok], A=w, B=x. Store row-major per token. ----
      const float4 bi = *(const float4*)(b_in + j0 + q4 * 4);
      f32x4 acc0; acc0[0] = bi.x; acc0[1] = bi.y; acc0[2] = bi.z; acc0[3] = bi.w;
      f32x4 acc[4] = {acc0, acc0, acc0, acc0};
#pragma unroll
      for (int tt = 0; tt < 4; ++tt)
#pragma unroll
        for (int ks = 0; ks < 4; ++ks)
          acc[tt] = __builtin_amdgcn_mfma_f32_16x16x32_bf16(wf[ks], xf[tt][ks], acc[tt], 0, 0, 0);
      // D: col=l16=token, row=q4*4+r = j offset
#pragma unroll
      for (int tt = 0; tt < 4; ++tt) {
        unsigned short* dst = qkv + ((tile_base + tt) * 16 + l16) * 512 + j0 + q4 * 4;
        uint2 o;
        o.x = pk2(acc[tt][0], acc[tt][1]);
        o.y = pk2(acc[tt][2], acc[tt][3]);
        *(uint2*)dst = o;
      }
    } else {
      // ---- v: SWAPPED operands. C[tok][j], A=x, B=w. ----
      const float bi = b_in[j0 + l16];
      f32x4 acc0; acc0[0] = bi; acc0[1] = bi; acc0[2] = bi; acc0[3] = bi;
      f32x4 acc[4] = {acc0, acc0, acc0, acc0};
#pragma unroll
      for (int tt = 0; tt < 4; ++tt)
#pragma unroll
        for (int ks = 0; ks < 4; ++ks)
          acc[tt] = __builtin_amdgcn_mfma_f32_16x16x32_bf16(xf[tt][ks], wf[ks], acc[tt], 0, 0, 0);
      // D: col=l16 = dim offset, row=q4*4+r = token -> b64 store
      const int jv = j0 - 512;
#pragma unroll
      for (int tt = 0; tt < 4; ++tt) {
        unsigned short* dst = vT + ((size_t)(tile_base + tt) * 256 + jv + l16) * 16 + q4 * 4;
        uint2 o;
        o.x = pk2(acc[tt][0], acc[tt][1]);
        o.y = pk2(acc[tt][2], acc[tt][3]);
        *(uint2*)dst = o;
      }
    }
  }
}

// ------------------------------------------------------------ attention ----
// grid (4096, 2). 512 threads = 8 waves; wave w -> head w.
#define PS_STRIDE 152  // 144 keys + 8 pad (bank spread; rows 16B-aligned)

__global__ __launch_bounds__(512, 8) void attn_out(
    const unsigned short* __restrict__ qkv,   // [tok][512] (q:0..256, k:256..512)
    const unsigned short* __restrict__ vT,    // [tile*256 + dim][16]
    const unsigned short* __restrict__ wob,   // w_out bf16 [128][256]
    const float* __restrict__ b_out,
    float* __restrict__ out) {
  __shared__ __align__(16) unsigned short ps_all[8][16 * PS_STRIDE];

  const int tid = threadIdx.x;
  const int wv = tid >> 6, lane = tid & 63;
  const int n = lane & 15, quad = lane >> 4;

  // XCD-aware swizzle: xcd = id&7 owns a contiguous vb-band of 8 rows.
  const int id = blockIdx.x;                 // 0..4095
  const int hb = (id >> 3) & 63;
  const int vb = (id & 7) * 8 + (id >> 9);
  const int bz = blockIdx.y;
  const int h = wv;

  unsigned short* ps = ps_all[wv];

  int nbrow[9];                              // wave-uniform -> SGPRs
  bool blk[9];
#pragma unroll
  for (int s0 = 0; s0 < 3; ++s0)
#pragma unroll
    for (int s1 = 0; s1 < 3; ++s1) {
      int hb2 = hb + s0 - 1, vb2 = vb + s1 - 1;
      blk[s0 * 3 + s1] = ((unsigned)hb2 > 63u) || ((unsigned)vb2 > 63u);
      int h2 = min(max(hb2, 0), 63), v2 = min(max(vb2, 0), 63);
      nbrow[s0 * 3 + s1] = ((bz * 64 + v2) * 64 + h2) * 16;
    }
  const int tb16 = ((bz * 64 + vb) * 64 + hb) * 16;
  const int i0q = n >> 2, i1q = n & 3;
  const float scale = 0.17677669529663687f;

  // Per-lane bias tables (indices compile-time in the unrolled loop).
  float a2c[3], b2c[12];
#pragma unroll
  for (int s0 = 0; s0 < 3; ++s0) {
    float a0 = (float)(s0 * 4 + quad - 4 - i0q);
    a2c[s0] = a0 * a0 * 0.0625f;
  }
#pragma unroll
  for (int s1 = 0; s1 < 3; ++s1)
#pragma unroll
    for (int r = 0; r < 4; ++r) {
      float b1 = (float)(s1 * 4 + r - 4 - i1q);
      b2c[s1 * 4 + r] = b1 * b1 * 0.0625f;
    }

  const unsigned short* qbase = qkv + (size_t)n * 512 + h * 32 + quad * 8;
  const bf16x8 qf = *(const bf16x8*)(qbase + (size_t)tb16 * 512);

  // ---- S^T = K*Q^T, max-free softmax, unnormalized P -> LDS ----
  float sum = 0.f;
#pragma unroll
  for (int s = 0; s < 9; ++s) {
    const int s0 = s / 3, s1 = s - s0 * 3;
    const bf16x8 kf = *(const bf16x8*)(qbase + 256 + (size_t)nbrow[s] * 512);
    f32x4 z; z[0] = 0.f; z[1] = 0.f; z[2] = 0.f; z[3] = 0.f;
    f32x4 sc = __builtin_amdgcn_mfma_f32_16x16x32_bf16(kf, qf, z, 0, 0, 0);
    unsigned short* prow = ps + n * PS_STRIDE + s * 16 + quad * 4;
    if (!blk[s]) {   // wave-uniform branch
      float p0 = __expf(fmaf(sc[0], scale, -(a2c[s0] + b2c[s1 * 4 + 0])));
      float p1 = __expf(fmaf(sc[1], scale, -(a2c[s0] + b2c[s1 * 4 + 1])));
      float p2 = __expf(fmaf(sc[2], scale, -(a2c[s0] + b2c[s1 * 4 + 2])));
      float p3 = __expf(fmaf(sc[3], scale, -(a2c[s0] + b2c[s1 * 4 + 3])));
      sum += (p0 + p1) + (p2 + p3);
      uint2 o; o.x = pk2(p0, p1); o.y = pk2(p2, p3);
      *(uint2*)prow = o;
    } else {
      uint2 o; o.x = 0u; o.y = 0u;
      *(uint2*)prow = o;
    }
  }
  sum += __shfl_xor(sum, 16);
  sum += __shfl_xor(sum, 32);
  const float inv = 1.f / sum;
  float inv4[4];
#pragma unroll
  for (int r = 0; r < 4; ++r)
    inv4[r] = __shfl(inv, (lane & 0x30) | (quad * 4 + r));

  // ---- PV: A from ps (b128), B direct from vT; tail masked ----
  bf16x8 af[5];
#pragma unroll
  for (int kc = 0; kc < 4; ++kc)
    af[kc] = *(const bf16x8*)(ps + n * PS_STRIDE + kc * 32 + quad * 8);
  af[4] = *(const bf16x8*)(ps + n * PS_STRIDE + 128 + (quad & 1) * 8);
  if (quad >= 2) { bf16x8 zf = {}; af[4] = zf; }   // keys 144..159 don't exist

  size_t vrow[9];
#pragma unroll
  for (int s = 0; s < 9; ++s) vrow[s] = (size_t)(nbrow[s] >> 4) * 4096;
  size_t vsel[4];
#pragma unroll
  for (int kc = 0; kc < 4; ++kc)
    vsel[kc] = (quad >> 1) ? vrow[kc * 2 + 1] : vrow[kc * 2];
  const int tok0 = (quad & 1) * 8;

#pragma unroll
  for (int d2 = 0; d2 < 2; ++d2) {
    const int voff = (h * 32 + d2 * 16 + n) * 16;
    f32x4 acc; acc[0] = 0.f; acc[1] = 0.f; acc[2] = 0.f; acc[3] = 0.f;
#pragma unroll
    for (int kc = 0; kc < 4; ++kc) {
      const bf16x8 vf = *(const bf16x8*)(vT + vsel[kc] + voff + tok0);
      acc = __builtin_amdgcn_mfma_f32_16x16x32_bf16(af[kc], vf, acc, 0, 0, 0);
    }
    {  // tail: keys 128..143 (af[4] zero on quads 2,3)
      const bf16x8 vf = *(const bf16x8*)(vT + vrow[8] + voff + tok0);
      acc = __builtin_amdgcn_mfma_f32_16x16x32_bf16(af[4], vf, acc, 0, 0, 0);
    }
    // D: row = quad*4+r = q token, col = n; normalize here, write ao slice
    // into this wave's own ps region (keys 0..31 area — af already in regs).
#pragma unroll
    for (int r = 0; r < 4; ++r)
      ps[(quad * 4 + r) * PS_STRIDE + d2 * 16 + n] = bf1(acc[r] * inv4[r]);
  }
  __syncthreads();

  // ---- out-projection: 8 MFMAs/wave, wave wv -> oc tile wv ----
  {
    const int oc = wv * 16 + n;
    const float bo = b_out[oc];
    f32x4 acc; acc[0] = bo; acc[1] = bo; acc[2] = bo; acc[3] = bo;
#pragma unroll
    for (int kc = 0; kc < 8; ++kc) {
      const bf16x8 a = *(const bf16x8*)(&ps_all[kc][n * PS_STRIDE + quad * 8]);
      const bf16x8 w8 = *(const bf16x8*)(wob + (size_t)oc * 256 + kc * 32 + quad * 8);
      acc = __builtin_amdgcn_mfma_f32_16x16x32_bf16(a, w8, acc, 0, 0, 0);
    }
    // D: row = quad*4+r = token (i0=quad, i1=r), col = n -> oc
#pragma unroll
    for (int r = 0; r < 4; ++r)
      out[(((size_t)bz * 128 + oc) * 256 + (vb * 4 + r)) * 256 + hb * 4 + quad] = acc[r];
  }
}

// ------------------------------------------------------------- launch ------
extern "C" void kernel_launch(void* const* d_in, const int* in_sizes, int n_in,
                              void* d_out, int out_size, void* d_ws, size_t ws_size,
                              hipStream_t stream) {
  const float* x     = (const float*)d_in[0];
  const float* w_in  = (const float*)d_in[1];
  const float* b_in  = (const float*)d_in[2];
  const float* w_out = (const float*)d_in[3];
  const float* b_out = (const float*)d_in[4];
  float* out = (float*)d_out;

  // ws: [0,196608)                w_in bf16
  //     [196608,262144)           w_out bf16 (65536 used)
  //     [262144,+134217728)       qkv bf16: 8192 tiles x 16 tok x 512 (q|k)
  //     [134479872,+67108864)     vT  bf16: 8192 tiles x 256 dims x 16 tok
  unsigned short* wbf = (unsigned short*)d_ws;
  unsigned short* wob = (unsigned short*)((char*)d_ws + 196608);
  unsigned short* qkv = (unsigned short*)((char*)d_ws + 262144);
  unsigned short* vT  = (unsigned short*)((char*)d_ws + 134479872);

  prep_w  <<<128, 256, 0, stream>>>(w_in, w_out, wbf, wob);
  qkv_proj<<<dim3(16, 64, 2), 256, 0, stream>>>(x, wbf, b_in, qkv, vT);
  attn_out<<<dim3(4096, 2), 512, 0, stream>>>(qkv, vT, wob, b_out, out);
}

// Round 6
// 468.641 us; speedup vs baseline: 1.0112x; 1.0112x over previous
//
#include <hip/hip_runtime.h>

// ---------------------------------------------------------------------------
// AttentionConvolution2D: B=2, DIN=128, H=W=256, BS=4 -> 64x64 tiles of 16
// tokens, NH=8, DH=32, DOUT=128.
//
//   prep_w   : w_in + w_out fp32 -> bf16 (ws)
//   qkv_proj : MFMA bf16 GEMM; q,k row-major per token (stride 512);
//              v transposed via swapped-operand MFMA (coalesced b64 stores).
//   attn     : 512 threads, one head per wave, NO barriers; max-free softmax;
//              unnormalized P -> per-wave LDS -> A-frags; PV from vT;
//              PV output OVERWRITES the q-slice of qkv (q is only ever read
//              by the block's own tile, and each wave reads/writes only its
//              own 32-dim slice -> race-free; saves a 67 MB ao buffer and
//              keeps ws within the 256 MiB budget that round 5 blew).
//   out_proj : strip kernel; C[tok][oc] = ao @ w_out^T + b_out, MFMA,
//              A-frags read from the q-slice at stride 512; stores merge
//              into full 64B lines (wpos spans 16 per block).
// ---------------------------------------------------------------------------

typedef __bf16 bf16x8 __attribute__((ext_vector_type(8)));
typedef __bf16 bf16x2 __attribute__((ext_vector_type(2)));
typedef float f32x4 __attribute__((ext_vector_type(4)));

__device__ __forceinline__ unsigned pk2(float a, float b) {
  bf16x2 v;
  v[0] = (__bf16)a;
  v[1] = (__bf16)b;  // v_cvt_pk_bf16_f32 (RNE)
  return __builtin_bit_cast(unsigned, v);
}
__device__ __forceinline__ unsigned short bf1(float a) {
  __bf16 v = (__bf16)a;
  return __builtin_bit_cast(unsigned short, v);
}

// ---------------------------------------------------------------- prep -----
__global__ __launch_bounds__(256) void prep_w(const float* __restrict__ w_in,
                                              const float* __restrict__ w_out,
                                              unsigned short* __restrict__ wbf,
                                              unsigned short* __restrict__ wob) {
  int idx = (blockIdx.x * 256 + threadIdx.x) * 4;
  const float* src; unsigned short* dst; int off;
  if (idx < 98304) { src = w_in;  dst = wbf; off = idx; }
  else             { src = w_out; dst = wob; off = idx - 98304; }
  float4 v = *(const float4*)(src + off);
  uint2 o;
  o.x = pk2(v.x, v.y);
  o.y = pk2(v.z, v.w);
  *(uint2*)(dst + off) = o;
}

// ------------------------------------------------------------ qkv proj -----
// grid (16, 64, 2): blockIdx.x = 4-tile strip along w, y = vb, z = b.
#define XS_STRIDE 136  // 128 + 8 pad

__global__ __launch_bounds__(256, 4) void qkv_proj(const float* __restrict__ x,
                                                   const unsigned short* __restrict__ wbf,
                                                   const float* __restrict__ b_in,
                                                   unsigned short* __restrict__ qkv,
                                                   unsigned short* __restrict__ vT) {
  __shared__ __align__(16) unsigned short xs[64 * XS_STRIDE];
  const int tid = threadIdx.x;
  const int strip = blockIdx.x, vb = blockIdx.y, b = blockIdx.z;
  const int w0 = strip * 16;
  const size_t xbase = ((size_t)b * 128) * 65536 + (size_t)(vb * 4) * 256 + (size_t)w0;

  // Stage x tile: 128 c x (4 i1 x 16 w), token-major bf16 in LDS.
#pragma unroll
  for (int it = 0; it < 8; ++it) {
    int flat = (it * 256 + tid) * 4;   // [0, 8192)
    int c = flat >> 6;
    int rem = flat & 63;
    int i1 = rem >> 4;
    int lw0 = rem & 15;
    const float4 v = *(const float4*)(x + xbase + (size_t)c * 65536 + i1 * 256 + lw0);
    float vv[4] = {v.x, v.y, v.z, v.w};
#pragma unroll
    for (int e = 0; e < 4; ++e) {
      int lw = lw0 + e;
      int u = ((lw >> 2) << 4) + ((lw & 3) << 2) + i1;  // tile*16 + i0*4 + i1
      xs[u * XS_STRIDE + c] = bf1(vv[e]);
    }
  }
  __syncthreads();

  const int wv = tid >> 6, lane = tid & 63;
  const int l16 = lane & 15, q4 = lane >> 4;
  const size_t tile_base = ((size_t)(b * 64 + vb)) * 64 + strip * 4;

  // Hoist all 16 x-fragments (jt-invariant) into registers.
  bf16x8 xf[4][4];
#pragma unroll
  for (int tt = 0; tt < 4; ++tt)
#pragma unroll
    for (int ks = 0; ks < 4; ++ks)
      xf[tt][ks] = *(const bf16x8*)(xs + (tt * 16 + l16) * XS_STRIDE + ks * 32 + q4 * 8);

#pragma unroll 1
  for (int jt = 0; jt < 12; ++jt) {
    const int j0 = wv * 192 + jt * 16;
    bf16x8 wf[4];
    const unsigned short* wr = wbf + (size_t)(j0 + l16) * 128 + q4 * 8;
#pragma unroll
    for (int ks = 0; ks < 4; ++ks) wf[ks] = *(const bf16x8*)(wr + ks * 32);

    if (j0 < 512) {
      // ---- q,k: C[j][tok], A=w, B=x. Store row-major per token. ----
      const float4 bi = *(const float4*)(b_in + j0 + q4 * 4);
      f32x4 acc0; acc0[0] = bi.x; acc0[1] = bi.y; acc0[2] = bi.z; acc0[3] = bi.w;
      f32x4 acc[4] = {acc0, acc0, acc0, acc0};
#pragma unroll
      for (int tt = 0; tt < 4; ++tt)
#pragma unroll
        for (int ks = 0; ks < 4; ++ks)
          acc[tt] = __builtin_amdgcn_mfma_f32_16x16x32_bf16(wf[ks], xf[tt][ks], acc[tt], 0, 0, 0);
#pragma unroll
      for (int tt = 0; tt < 4; ++tt) {
        unsigned short* dst = qkv + ((tile_base + tt) * 16 + l16) * 512 + j0 + q4 * 4;
        uint2 o;
        o.x = pk2(acc[tt][0], acc[tt][1]);
        o.y = pk2(acc[tt][2], acc[tt][3]);
        *(uint2*)dst = o;
      }
    } else {
      // ---- v: SWAPPED operands. C[tok][j], A=x, B=w. ----
      const float bi = b_in[j0 + l16];
      f32x4 acc0; acc0[0] = bi; acc0[1] = bi; acc0[2] = bi; acc0[3] = bi;
      f32x4 acc[4] = {acc0, acc0, acc0, acc0};
#pragma unroll
      for (int tt = 0; tt < 4; ++tt)
#pragma unroll
        for (int ks = 0; ks < 4; ++ks)
          acc[tt] = __builtin_amdgcn_mfma_f32_16x16x32_bf16(xf[tt][ks], wf[ks], acc[tt], 0, 0, 0);
      const int jv = j0 - 512;
#pragma unroll
      for (int tt = 0; tt < 4; ++tt) {
        unsigned short* dst = vT + ((size_t)(tile_base + tt) * 256 + jv + l16) * 16 + q4 * 4;
        uint2 o;
        o.x = pk2(acc[tt][0], acc[tt][1]);
        o.y = pk2(acc[tt][2], acc[tt][3]);
        *(uint2*)dst = o;
      }
    }
  }
}

// ------------------------------------------------------------ attention ----
// grid (4096, 2). 512 threads = 8 waves; wave w -> head w. NO barriers.
#define PS_STRIDE 152  // 144 keys + 8 pad

__global__ __launch_bounds__(512, 8) void attn(
    unsigned short* __restrict__ qkv,         // [tok][512] (q:0..256, k:256..512)
    const unsigned short* __restrict__ vT) {  // [tile*256 + dim][16]
  __shared__ __align__(16) unsigned short ps_all[8][16 * PS_STRIDE];

  const int tid = threadIdx.x;
  const int wv = tid >> 6, lane = tid & 63;
  const int n = lane & 15, quad = lane >> 4;

  // XCD-aware swizzle (fetch locality; all writes here are full-line).
  const int id = blockIdx.x;                 // 0..4095
  const int hb = (id >> 3) & 63;
  const int vb = (id & 7) * 8 + (id >> 9);
  const int bz = blockIdx.y;
  const int h = wv;

  unsigned short* ps = ps_all[wv];

  int nbrow[9];
  bool blk[9];
#pragma unroll
  for (int s0 = 0; s0 < 3; ++s0)
#pragma unroll
    for (int s1 = 0; s1 < 3; ++s1) {
      int hb2 = hb + s0 - 1, vb2 = vb + s1 - 1;
      blk[s0 * 3 + s1] = ((unsigned)hb2 > 63u) || ((unsigned)vb2 > 63u);
      int h2 = min(max(hb2, 0), 63), v2 = min(max(vb2, 0), 63);
      nbrow[s0 * 3 + s1] = ((bz * 64 + v2) * 64 + h2) * 16;
    }
  const int tb16 = ((bz * 64 + vb) * 64 + hb) * 16;
  const int i0q = n >> 2, i1q = n & 3;
  const float scale = 0.17677669529663687f;

  float a2c[3], b2c[12];
#pragma unroll
  for (int s0 = 0; s0 < 3; ++s0) {
    float a0 = (float)(s0 * 4 + quad - 4 - i0q);
    a2c[s0] = a0 * a0 * 0.0625f;
  }
#pragma unroll
  for (int s1 = 0; s1 < 3; ++s1)
#pragma unroll
    for (int r = 0; r < 4; ++r) {
      float b1 = (float)(s1 * 4 + r - 4 - i1q);
      b2c[s1 * 4 + r] = b1 * b1 * 0.0625f;
    }

  const unsigned short* qbase = qkv + (size_t)n * 512 + h * 32 + quad * 8;
  const bf16x8 qf = *(const bf16x8*)(qbase + (size_t)tb16 * 512);

  // ---- S^T = K*Q^T, max-free softmax, unnormalized P -> LDS ----
  float sum = 0.f;
#pragma unroll
  for (int s = 0; s < 9; ++s) {
    const int s0 = s / 3, s1 = s - s0 * 3;
    const bf16x8 kf = *(const bf16x8*)(qbase + 256 + (size_t)nbrow[s] * 512);
    f32x4 z; z[0] = 0.f; z[1] = 0.f; z[2] = 0.f; z[3] = 0.f;
    f32x4 sc = __builtin_amdgcn_mfma_f32_16x16x32_bf16(kf, qf, z, 0, 0, 0);
    unsigned short* prow = ps + n * PS_STRIDE + s * 16 + quad * 4;
    if (!blk[s]) {   // wave-uniform branch
      float p0 = __expf(fmaf(sc[0], scale, -(a2c[s0] + b2c[s1 * 4 + 0])));
      float p1 = __expf(fmaf(sc[1], scale, -(a2c[s0] + b2c[s1 * 4 + 1])));
      float p2 = __expf(fmaf(sc[2], scale, -(a2c[s0] + b2c[s1 * 4 + 2])));
      float p3 = __expf(fmaf(sc[3], scale, -(a2c[s0] + b2c[s1 * 4 + 3])));
      sum += (p0 + p1) + (p2 + p3);
      uint2 o; o.x = pk2(p0, p1); o.y = pk2(p2, p3);
      *(uint2*)prow = o;
    } else {
      uint2 o; o.x = 0u; o.y = 0u;
      *(uint2*)prow = o;
    }
  }
  sum += __shfl_xor(sum, 16);
  sum += __shfl_xor(sum, 32);
  const float inv = 1.f / sum;
  float inv4[4];
#pragma unroll
  for (int r = 0; r < 4; ++r)
    inv4[r] = __shfl(inv, (lane & 0x30) | (quad * 4 + r));

  // ---- PV: A from ps (b128), B direct from vT; tail masked ----
  bf16x8 af[5];
#pragma unroll
  for (int kc = 0; kc < 4; ++kc)
    af[kc] = *(const bf16x8*)(ps + n * PS_STRIDE + kc * 32 + quad * 8);
  af[4] = *(const bf16x8*)(ps + n * PS_STRIDE + 128 + (quad & 1) * 8);
  if (quad >= 2) { bf16x8 zf = {}; af[4] = zf; }   // keys 144..159 don't exist

  size_t vrow[9];
#pragma unroll
  for (int s = 0; s < 9; ++s) vrow[s] = (size_t)(nbrow[s] >> 4) * 4096;
  size_t vsel[4];
#pragma unroll
  for (int kc = 0; kc < 4; ++kc)
    vsel[kc] = (quad >> 1) ? vrow[kc * 2 + 1] : vrow[kc * 2];
  const int tok0 = (quad & 1) * 8;

#pragma unroll
  for (int d2 = 0; d2 < 2; ++d2) {
    const int voff = (h * 32 + d2 * 16 + n) * 16;
    f32x4 acc; acc[0] = 0.f; acc[1] = 0.f; acc[2] = 0.f; acc[3] = 0.f;
#pragma unroll
    for (int kc = 0; kc < 4; ++kc) {
      const bf16x8 vf = *(const bf16x8*)(vT + vsel[kc] + voff + tok0);
      acc = __builtin_amdgcn_mfma_f32_16x16x32_bf16(af[kc], vf, acc, 0, 0, 0);
    }
    {  // tail: keys 128..143
      const bf16x8 vf = *(const bf16x8*)(vT + vrow[8] + voff + tok0);
      acc = __builtin_amdgcn_mfma_f32_16x16x32_bf16(af[4], vf, acc, 0, 0, 0);
    }
    // D: row = quad*4+r = q token, col = n = dim; normalize + store bf16
    // INTO THE q-SLICE of this tile (dead after the qf load above; each wave
    // touches only its own 32-dim slice -> race-free, full-line writes).
#pragma unroll
    for (int r = 0; r < 4; ++r)
      qkv[(size_t)(tb16 + quad * 4 + r) * 512 + h * 32 + d2 * 16 + n] =
          bf1(acc[r] * inv4[r]);
  }
}

// ------------------------------------------------------------ out proj -----
// grid (16, 64, 2): strip of 4 tiles. C[tok][oc] = ao @ w_out^T + b_out,
// where ao lives in the q-slice of qkv (stride 512 per token).
__global__ __launch_bounds__(256, 4) void out_proj(
    const unsigned short* __restrict__ qkv,   // ao in [tok][512], dims 0..256
    const unsigned short* __restrict__ wob,   // [oc][256]
    const float* __restrict__ b_out,
    float* __restrict__ out) {
  const int tid = threadIdx.x;
  const int wv = tid >> 6, lane = tid & 63;
  const int n = lane & 15, quad = lane >> 4;
  const int strip = blockIdx.x, vb = blockIdx.y, bz = blockIdx.z;
  const size_t tile_base = ((size_t)(bz * 64 + vb)) * 64 + strip * 4;

  // B-fragments: w_out rows for this wave's two oc tiles (L2-hot).
  bf16x8 wf[2][8];
#pragma unroll
  for (int ot = 0; ot < 2; ++ot) {
    const int oc = (wv * 2 + ot) * 16 + n;
#pragma unroll
    for (int kc = 0; kc < 8; ++kc)
      wf[ot][kc] = *(const bf16x8*)(wob + (size_t)oc * 256 + kc * 32 + quad * 8);
  }
  float bo[2] = {b_out[(wv * 2 + 0) * 16 + n], b_out[(wv * 2 + 1) * 16 + n]};

#pragma unroll
  for (int tt = 0; tt < 4; ++tt) {
    // A-fragments: ao token rows (q-slice), direct global b128.
    bf16x8 af[8];
    const unsigned short* ar = qkv + ((tile_base + tt) * 16 + n) * 512 + quad * 8;
#pragma unroll
    for (int kc = 0; kc < 8; ++kc) af[kc] = *(const bf16x8*)(ar + kc * 32);

#pragma unroll
    for (int ot = 0; ot < 2; ++ot) {
      f32x4 acc; acc[0] = bo[ot]; acc[1] = bo[ot]; acc[2] = bo[ot]; acc[3] = bo[ot];
#pragma unroll
      for (int kc = 0; kc < 8; ++kc)
        acc = __builtin_amdgcn_mfma_f32_16x16x32_bf16(af[kc], wf[ot][kc], acc, 0, 0, 0);
      // D: row = quad*4+r = token (i0=quad, i1=r), col = n -> oc
      const int oc = (wv * 2 + ot) * 16 + n;
#pragma unroll
      for (int r = 0; r < 4; ++r)
        out[(((size_t)bz * 128 + oc) * 256 + (vb * 4 + r)) * 256 +
            strip * 16 + tt * 4 + quad] = acc[r];
    }
  }
}

// ------------------------------------------------------------- launch ------
extern "C" void kernel_launch(void* const* d_in, const int* in_sizes, int n_in,
                              void* d_out, int out_size, void* d_ws, size_t ws_size,
                              hipStream_t stream) {
  const float* x     = (const float*)d_in[0];
  const float* w_in  = (const float*)d_in[1];
  const float* b_in  = (const float*)d_in[2];
  const float* w_out = (const float*)d_in[3];
  const float* b_out = (const float*)d_in[4];
  float* out = (float*)d_out;

  // ws: [0,196608)                w_in bf16
  //     [196608,262144)           w_out bf16 (65536 used)
  //     [262144,+134217728)       qkv bf16: 8192 tiles x 16 tok x 512 (q|k);
  //                               q-slice is reused as attention-output ao
  //     [134479872,+67108864)     vT  bf16: 8192 tiles x 256 dims x 16 tok
  // total 201588736 B (= the footprint that passed rounds 1-4)
  unsigned short* wbf = (unsigned short*)d_ws;
  unsigned short* wob = (unsigned short*)((char*)d_ws + 196608);
  unsigned short* qkv = (unsigned short*)((char*)d_ws + 262144);
  unsigned short* vT  = (unsigned short*)((char*)d_ws + 134479872);

  prep_w  <<<128, 256, 0, stream>>>(w_in, w_out, wbf, wob);
  qkv_proj<<<dim3(16, 64, 2), 256, 0, stream>>>(x, wbf, b_in, qkv, vT);
  attn    <<<dim3(4096, 2), 512, 0, stream>>>(qkv, vT);
  out_proj<<<dim3(16, 64, 2), 256, 0, stream>>>(qkv, wob, b_out, out);
}

// Round 7
// 421.714 us; speedup vs baseline: 1.1237x; 1.1113x over previous
//
#include <hip/hip_runtime.h>

// ---------------------------------------------------------------------------
// AttentionConvolution2D: B=2, DIN=128, H=W=256, BS=4 -> 64x64 tiles of 16
// tokens, NH=8, DH=32, DOUT=128.
//
// HEAD-MAJOR intermediate layouts so every attention-phase wave access is a
// contiguous ~1KB burst (round 6 showed 64B-granularity gathers cap attn at
// ~1 TB/s effective):
//   qk[tile]: 16KB = q[h][tok16][dim32] (8KB) | k[h][tok16][dim32] (8KB)
//   vT[tile]: 8KB  = [h][dim32][tok16]
//   attn PV output overwrites the q-slice [h][tok][32] of its own tile.
//
//   prep_w   : w_in + w_out fp32 -> bf16 (ws)
//   qkv_proj : MFMA bf16 GEMM -> qk / vT (v via swapped-operand MFMA)
//   attn     : 512 thr, head per wave, no barriers; max-free softmax;
//              unnormalized P -> per-wave LDS -> A-frags; PV from vT.
//   out_proj : strip kernel, C[tok][oc] = ao @ w_out^T + b_out (MFMA).
// ---------------------------------------------------------------------------

typedef __bf16 bf16x8 __attribute__((ext_vector_type(8)));
typedef __bf16 bf16x2 __attribute__((ext_vector_type(2)));
typedef float f32x4 __attribute__((ext_vector_type(4)));

__device__ __forceinline__ unsigned pk2(float a, float b) {
  bf16x2 v;
  v[0] = (__bf16)a;
  v[1] = (__bf16)b;  // v_cvt_pk_bf16_f32 (RNE)
  return __builtin_bit_cast(unsigned, v);
}
__device__ __forceinline__ unsigned short bf1(float a) {
  __bf16 v = (__bf16)a;
  return __builtin_bit_cast(unsigned short, v);
}

// ---------------------------------------------------------------- prep -----
__global__ __launch_bounds__(256) void prep_w(const float* __restrict__ w_in,
                                              const float* __restrict__ w_out,
                                              unsigned short* __restrict__ wbf,
                                              unsigned short* __restrict__ wob) {
  int idx = (blockIdx.x * 256 + threadIdx.x) * 4;
  const float* src; unsigned short* dst; int off;
  if (idx < 98304) { src = w_in;  dst = wbf; off = idx; }
  else             { src = w_out; dst = wob; off = idx - 98304; }
  float4 v = *(const float4*)(src + off);
  uint2 o;
  o.x = pk2(v.x, v.y);
  o.y = pk2(v.z, v.w);
  *(uint2*)(dst + off) = o;
}

// ------------------------------------------------------------ qkv proj -----
// grid (16, 64, 2): blockIdx.x = 4-tile strip along w, y = vb, z = b.
#define XS_STRIDE 136  // 128 + 8 pad

__global__ __launch_bounds__(256, 4) void qkv_proj(const float* __restrict__ x,
                                                   const unsigned short* __restrict__ wbf,
                                                   const float* __restrict__ b_in,
                                                   unsigned short* __restrict__ qk,
                                                   unsigned short* __restrict__ vT) {
  __shared__ __align__(16) unsigned short xs[64 * XS_STRIDE];
  const int tid = threadIdx.x;
  const int strip = blockIdx.x, vb = blockIdx.y, b = blockIdx.z;
  const int w0 = strip * 16;
  const size_t xbase = ((size_t)b * 128) * 65536 + (size_t)(vb * 4) * 256 + (size_t)w0;

  // Stage x tile: 128 c x (4 i1 x 16 w), token-major bf16 in LDS.
#pragma unroll
  for (int it = 0; it < 8; ++it) {
    int flat = (it * 256 + tid) * 4;   // [0, 8192)
    int c = flat >> 6;
    int rem = flat & 63;
    int i1 = rem >> 4;
    int lw0 = rem & 15;
    const float4 v = *(const float4*)(x + xbase + (size_t)c * 65536 + i1 * 256 + lw0);
    float vv[4] = {v.x, v.y, v.z, v.w};
#pragma unroll
    for (int e = 0; e < 4; ++e) {
      int lw = lw0 + e;
      int u = ((lw >> 2) << 4) + ((lw & 3) << 2) + i1;  // tile*16 + i0*4 + i1
      xs[u * XS_STRIDE + c] = bf1(vv[e]);
    }
  }
  __syncthreads();

  const int wv = tid >> 6, lane = tid & 63;
  const int l16 = lane & 15, q4 = lane >> 4;
  const size_t tile_base = ((size_t)(b * 64 + vb)) * 64 + strip * 4;

  // Hoist all 16 x-fragments (jt-invariant) into registers.
  bf16x8 xf[4][4];
#pragma unroll
  for (int tt = 0; tt < 4; ++tt)
#pragma unroll
    for (int ks = 0; ks < 4; ++ks)
      xf[tt][ks] = *(const bf16x8*)(xs + (tt * 16 + l16) * XS_STRIDE + ks * 32 + q4 * 8);

#pragma unroll 1
  for (int jt = 0; jt < 12; ++jt) {
    const int j0 = wv * 192 + jt * 16;
    bf16x8 wf[4];
    const unsigned short* wr = wbf + (size_t)(j0 + l16) * 128 + q4 * 8;
#pragma unroll
    for (int ks = 0; ks < 4; ++ks) wf[ks] = *(const bf16x8*)(wr + ks * 32);

    if (j0 < 512) {
      // ---- q,k: C[j][tok], A=w, B=x -> qk[tile]{q|k}[h][tok][32] ----
      const float4 bi = *(const float4*)(b_in + j0 + q4 * 4);
      f32x4 acc0; acc0[0] = bi.x; acc0[1] = bi.y; acc0[2] = bi.z; acc0[3] = bi.w;
      f32x4 acc[4] = {acc0, acc0, acc0, acc0};
#pragma unroll
      for (int tt = 0; tt < 4; ++tt)
#pragma unroll
        for (int ks = 0; ks < 4; ++ks)
          acc[tt] = __builtin_amdgcn_mfma_f32_16x16x32_bf16(wf[ks], xf[tt][ks], acc[tt], 0, 0, 0);
      // D: col=l16=token, row=q4*4+r = j offset
      const int seg = (j0 < 256) ? 0 : 4096;          // q | k half
      const int hh = (j0 >> 5) & 7;                   // head
      const int doff = (j0 & 16) + q4 * 4;            // dim-in-head
#pragma unroll
      for (int tt = 0; tt < 4; ++tt) {
        unsigned short* dst = qk + (tile_base + tt) * 8192 + seg + hh * 512 +
                              l16 * 32 + doff;
        uint2 o;
        o.x = pk2(acc[tt][0], acc[tt][1]);
        o.y = pk2(acc[tt][2], acc[tt][3]);
        *(uint2*)dst = o;
      }
    } else {
      // ---- v: SWAPPED operands. C[tok][j] -> vT[tile][h][dim][tok] ----
      const float bi = b_in[j0 + l16];
      f32x4 acc0; acc0[0] = bi; acc0[1] = bi; acc0[2] = bi; acc0[3] = bi;
      f32x4 acc[4] = {acc0, acc0, acc0, acc0};
#pragma unroll
      for (int tt = 0; tt < 4; ++tt)
#pragma unroll
        for (int ks = 0; ks < 4; ++ks)
          acc[tt] = __builtin_amdgcn_mfma_f32_16x16x32_bf16(xf[tt][ks], wf[ks], acc[tt], 0, 0, 0);
      // D: col=l16 -> dim jv+l16, row=q4*4+r = token -> b64 store
      const int jv = j0 - 512;
      const int hh = jv >> 5;
      const int din = (jv & 16) + l16;                // dim-in-head
#pragma unroll
      for (int tt = 0; tt < 4; ++tt) {
        unsigned short* dst = vT + (tile_base + tt) * 4096 + hh * 512 +
                              din * 16 + q4 * 4;
        uint2 o;
        o.x = pk2(acc[tt][0], acc[tt][1]);
        o.y = pk2(acc[tt][2], acc[tt][3]);
        *(uint2*)dst = o;
      }
    }
  }
}

// ------------------------------------------------------------ attention ----
// grid (4096, 2). 512 threads = 8 waves; wave w -> head w. NO barriers.
#define PS_STRIDE 152  // 144 keys + 8 pad

__global__ __launch_bounds__(512, 8) void attn(
    unsigned short* __restrict__ qk,          // [tile]{q|k}[h][tok][32]
    const unsigned short* __restrict__ vT) {  // [tile][h][dim][tok]
  __shared__ __align__(16) unsigned short ps_all[8][16 * PS_STRIDE];

  const int tid = threadIdx.x;
  const int wv = tid >> 6, lane = tid & 63;
  const int n = lane & 15, quad = lane >> 4;

  // XCD-aware swizzle (fetch locality; all writes here are full-line).
  const int id = blockIdx.x;                 // 0..4095
  const int hb = (id >> 3) & 63;
  const int vb = (id & 7) * 8 + (id >> 9);
  const int bz = blockIdx.y;
  const int h = wv;

  unsigned short* ps = ps_all[wv];

  int nbtile[9];
  bool blk[9];
#pragma unroll
  for (int s0 = 0; s0 < 3; ++s0)
#pragma unroll
    for (int s1 = 0; s1 < 3; ++s1) {
      int hb2 = hb + s0 - 1, vb2 = vb + s1 - 1;
      blk[s0 * 3 + s1] = ((unsigned)hb2 > 63u) || ((unsigned)vb2 > 63u);
      int h2 = min(max(hb2, 0), 63), v2 = min(max(vb2, 0), 63);
      nbtile[s0 * 3 + s1] = (bz * 64 + v2) * 64 + h2;
    }
  const int mytile = (bz * 64 + vb) * 64 + hb;
  const int i0q = n >> 2, i1q = n & 3;
  const float scale = 0.17677669529663687f;

  float a2c[3], b2c[12];
#pragma unroll
  for (int s0 = 0; s0 < 3; ++s0) {
    float a0 = (float)(s0 * 4 + quad - 4 - i0q);
    a2c[s0] = a0 * a0 * 0.0625f;
  }
#pragma unroll
  for (int s1 = 0; s1 < 3; ++s1)
#pragma unroll
    for (int r = 0; r < 4; ++r) {
      float b1 = (float)(s1 * 4 + r - 4 - i1q);
      b2c[s1 * 4 + r] = b1 * b1 * 0.0625f;
    }

  // q / k fragment loads: 1KB contiguous per wave.
  const int fragoff = h * 512 + n * 32 + quad * 8;
  const bf16x8 qf = *(const bf16x8*)(qk + (size_t)mytile * 8192 + fragoff);
  const unsigned short* kbase = qk + 4096 + fragoff;

  // ---- S^T = K*Q^T, max-free softmax, unnormalized P -> LDS ----
  float sum = 0.f;
#pragma unroll
  for (int s = 0; s < 9; ++s) {
    const int s0 = s / 3, s1 = s - s0 * 3;
    const bf16x8 kf = *(const bf16x8*)(kbase + (size_t)nbtile[s] * 8192);
    f32x4 z; z[0] = 0.f; z[1] = 0.f; z[2] = 0.f; z[3] = 0.f;
    f32x4 sc = __builtin_amdgcn_mfma_f32_16x16x32_bf16(kf, qf, z, 0, 0, 0);
    unsigned short* prow = ps + n * PS_STRIDE + s * 16 + quad * 4;
    if (!blk[s]) {   // wave-uniform branch
      float p0 = __expf(fmaf(sc[0], scale, -(a2c[s0] + b2c[s1 * 4 + 0])));
      float p1 = __expf(fmaf(sc[1], scale, -(a2c[s0] + b2c[s1 * 4 + 1])));
      float p2 = __expf(fmaf(sc[2], scale, -(a2c[s0] + b2c[s1 * 4 + 2])));
      float p3 = __expf(fmaf(sc[3], scale, -(a2c[s0] + b2c[s1 * 4 + 3])));
      sum += (p0 + p1) + (p2 + p3);
      uint2 o; o.x = pk2(p0, p1); o.y = pk2(p2, p3);
      *(uint2*)prow = o;
    } else {
      uint2 o; o.x = 0u; o.y = 0u;
      *(uint2*)prow = o;
    }
  }
  sum += __shfl_xor(sum, 16);
  sum += __shfl_xor(sum, 32);
  const float inv = 1.f / sum;
  float inv4[4];
#pragma unroll
  for (int r = 0; r < 4; ++r)
    inv4[r] = __shfl(inv, (lane & 0x30) | (quad * 4 + r));

  // ---- PV: A from ps (b128), B direct from vT; tail masked ----
  bf16x8 af[5];
#pragma unroll
  for (int kc = 0; kc < 4; ++kc)
    af[kc] = *(const bf16x8*)(ps + n * PS_STRIDE + kc * 32 + quad * 8);
  af[4] = *(const bf16x8*)(ps + n * PS_STRIDE + 128 + (quad & 1) * 8);
  if (quad >= 2) { bf16x8 zf = {}; af[4] = zf; }   // keys 144..159 don't exist

  size_t vrow[9];
#pragma unroll
  for (int s = 0; s < 9; ++s) vrow[s] = (size_t)nbtile[s] * 4096 + h * 512;
  size_t vsel[4];
#pragma unroll
  for (int kc = 0; kc < 4; ++kc)
    vsel[kc] = (quad >> 1) ? vrow[kc * 2 + 1] : vrow[kc * 2];
  const int tok0 = (quad & 1) * 8;

#pragma unroll
  for (int d2 = 0; d2 < 2; ++d2) {
    const int voff = (d2 * 16 + n) * 16;    // dim-in-head * 16 tokens
    f32x4 acc; acc[0] = 0.f; acc[1] = 0.f; acc[2] = 0.f; acc[3] = 0.f;
#pragma unroll
    for (int kc = 0; kc < 4; ++kc) {
      const bf16x8 vf = *(const bf16x8*)(vT + vsel[kc] + voff + tok0);
      acc = __builtin_amdgcn_mfma_f32_16x16x32_bf16(af[kc], vf, acc, 0, 0, 0);
    }
    {  // tail: keys 128..143
      const bf16x8 vf = *(const bf16x8*)(vT + vrow[8] + voff + tok0);
      acc = __builtin_amdgcn_mfma_f32_16x16x32_bf16(af[4], vf, acc, 0, 0, 0);
    }
    // D: row = quad*4+r = q token, col = n = dim; normalize + store bf16
    // into this tile's q-slice (wave h owns slice h -> race-free, the
    // wave's 8 stores cover a contiguous 1KB region).
#pragma unroll
    for (int r = 0; r < 4; ++r)
      qk[(size_t)mytile * 8192 + h * 512 + (quad * 4 + r) * 32 + d2 * 16 + n] =
          bf1(acc[r] * inv4[r]);
  }
}

// ------------------------------------------------------------ out proj -----
// grid (16, 64, 2): strip of 4 tiles. C[tok][oc] = ao @ w_out^T + b_out,
// ao = q-slice of qk: [tile][h][tok][32] (k-dim order h*32+d matches w_out).
__global__ __launch_bounds__(256, 4) void out_proj(
    const unsigned short* __restrict__ qk,
    const unsigned short* __restrict__ wob,   // [oc][256]
    const float* __restrict__ b_out,
    float* __restrict__ out) {
  const int tid = threadIdx.x;
  const int wv = tid >> 6, lane = tid & 63;
  const int n = lane & 15, quad = lane >> 4;
  const int strip = blockIdx.x, vb = blockIdx.y, bz = blockIdx.z;
  const size_t tile_base = ((size_t)(bz * 64 + vb)) * 64 + strip * 4;

  // B-fragments: w_out rows for this wave's two oc tiles (L2-hot).
  bf16x8 wf[2][8];
#pragma unroll
  for (int ot = 0; ot < 2; ++ot) {
    const int oc = (wv * 2 + ot) * 16 + n;
#pragma unroll
    for (int kc = 0; kc < 8; ++kc)
      wf[ot][kc] = *(const bf16x8*)(wob + (size_t)oc * 256 + kc * 32 + quad * 8);
  }
  float bo[2] = {b_out[(wv * 2 + 0) * 16 + n], b_out[(wv * 2 + 1) * 16 + n]};

#pragma unroll
  for (int tt = 0; tt < 4; ++tt) {
    // A-fragments: [tile][kc=head][tok=n][quad*8] -> 1KB bursts.
    bf16x8 af[8];
    const unsigned short* ar = qk + (tile_base + tt) * 8192 + n * 32 + quad * 8;
#pragma unroll
    for (int kc = 0; kc < 8; ++kc) af[kc] = *(const bf16x8*)(ar + kc * 512);

#pragma unroll
    for (int ot = 0; ot < 2; ++ot) {
      f32x4 acc; acc[0] = bo[ot]; acc[1] = bo[ot]; acc[2] = bo[ot]; acc[3] = bo[ot];
#pragma unroll
      for (int kc = 0; kc < 8; ++kc)
        acc = __builtin_amdgcn_mfma_f32_16x16x32_bf16(af[kc], wf[ot][kc], acc, 0, 0, 0);
      // D: row = quad*4+r = token (i0=quad, i1=r), col = n -> oc
      const int oc = (wv * 2 + ot) * 16 + n;
#pragma unroll
      for (int r = 0; r < 4; ++r)
        out[(((size_t)bz * 128 + oc) * 256 + (vb * 4 + r)) * 256 +
            strip * 16 + tt * 4 + quad] = acc[r];
    }
  }
}

// ------------------------------------------------------------- launch ------
extern "C" void kernel_launch(void* const* d_in, const int* in_sizes, int n_in,
                              void* d_out, int out_size, void* d_ws, size_t ws_size,
                              hipStream_t stream) {
  const float* x     = (const float*)d_in[0];
  const float* w_in  = (const float*)d_in[1];
  const float* b_in  = (const float*)d_in[2];
  const float* w_out = (const float*)d_in[3];
  const float* b_out = (const float*)d_in[4];
  float* out = (float*)d_out;

  // ws: [0,196608)                w_in bf16
  //     [196608,262144)           w_out bf16 (65536 used)
  //     [262144,+134217728)       qk bf16: 8192 tiles x 8192 shorts
  //                               (q-slice reused as attention output)
  //     [134479872,+67108864)     vT bf16: 8192 tiles x 4096 shorts
  // total 201588736 B (same footprint as rounds 1-4, fits)
  unsigned short* wbf = (unsigned short*)d_ws;
  unsigned short* wob = (unsigned short*)((char*)d_ws + 196608);
  unsigned short* qk  = (unsigned short*)((char*)d_ws + 262144);
  unsigned short* vT  = (unsigned short*)((char*)d_ws + 134479872);

  prep_w  <<<128, 256, 0, stream>>>(w_in, w_out, wbf, wob);
  qkv_proj<<<dim3(16, 64, 2), 256, 0, stream>>>(x, wbf, b_in, qk, vT);
  attn    <<<dim3(4096, 2), 512, 0, stream>>>(qk, vT);
  out_proj<<<dim3(16, 64, 2), 256, 0, stream>>>(qk, wob, b_out, out);
}